// Round 19
// baseline (520.495 us; speedup 1.0000x reference)
//
#include <hip/hip_runtime.h>

#define NV   50000
#define NR   5
#define NT   8
#define CIN  64
#define COUT 64
#define BARY (NR*NT*3)      // 120
#define BK_ELEMS (NR*CIN*NT*COUT)   // 163840 fp16 (320 KB) — L2-resident
#define BM2  64
#define NBLK2 ((NV + BM2 - 1) / BM2)   // 782
#define NCH  80             // chunks: (j 0..7) x (icc 0..9), K=32 each

#define WL_BYTES 262144
#define SIG16_BYTES (NV*CIN*2)                            // 6.4 MB
#define WS_NEED8 (WL_BYTES + 2u*BK_ELEMS + SIG16_BYTES)   // ~7.0 MB

typedef _Float16 f16x8 __attribute__((ext_vector_type(8)));
typedef _Float16 f16x4 __attribute__((ext_vector_type(4)));
typedef float    f32x4 __attribute__((ext_vector_type(4)));

// ---------- K0a: kernel -> fp16 ws, chunked [icc][col=m*64+d][ck] (v7 layout) ----------
__global__ __launch_bounds__(256) void build_bk7(
    const float* __restrict__ kern, _Float16* __restrict__ bk)
{
    int e   = blockIdx.x * 256 + threadIdx.x;   // icc*16384 + col*32 + ck
    int ck  = e & 31;
    int col = (e >> 5) & 511;
    int icc = e >> 14;
    int i   = icc >> 1;
    int c   = (icc & 1) * 32 + ck;
    int m   = col >> 6;
    int d   = col & 63;
    bk[e] = (_Float16)kern[((i * NT + m) * CIN + c) * COUT + d];
}

// ---------- K0b: signal -> fp16 ----------
__global__ __launch_bounds__(256) void build_sig16(
    const float* __restrict__ signal, _Float16* __restrict__ sig16)
{
    int e = blockIdx.x * 256 + threadIdx.x;
    sig16[e] = (_Float16)signal[e];
}

// ---------- main v15 = v7 (323us proven) with ONE barrier/chunk (A dbuf'd) ----------
__global__ __launch_bounds__(512, 4) void geo_mfma15(
    const float* __restrict__ bary_w,
    const int*   __restrict__ bary_idx,
    const _Float16* __restrict__ sig16,
    const _Float16* __restrict__ bk,
    float* __restrict__ out,
    int*   __restrict__ wl)
{
    __shared__ __align__(16) _Float16 Blds[2][16384];   // 2 x 32 KB
    __shared__ __align__(16) _Float16 Axs[2][4][BM2][8];// 2 x 4 KB (dbuf)
    __shared__ float nrm[BM2][NT];                      // 2 KB
    __shared__ int   besti[BM2];

    const int tid  = threadIdx.x;
    const int lane = tid & 63;
    const int wn   = tid >> 6;         // wave wn owns rotation k=wn
    const int g    = lane >> 4;
    const int l15  = lane & 15;
    const int vbase = blockIdx.x * BM2;

    // A-staging mapping: thread -> (vertex vt, ck-quad cq); 4 channels each
    const int vt = tid >> 3;
    const int cq = tid & 7;
    const int v_mine = vbase + vt;
    const bool v_ok = (v_mine < NV);

    f32x4 acc[4][4];
    {
        f32x4 z = {0.f, 0.f, 0.f, 0.f};
        #pragma unroll
        for (int mf = 0; mf < 4; ++mf)
            #pragma unroll
            for (int nf = 0; nf < 4; ++nf) acc[mf][nf] = z;
    }

    struct Gen { float w0, w1, w2; int i0, i1, i2; };
    auto LOADGEN = [&](int it2) -> Gen {
        Gen gg;
        const int itc = (it2 < NCH) ? it2 : (NCH - 1);
        const int j2   = itc / 10;
        const int icc2 = itc - j2 * 10;
        const int i2   = icc2 >> 1;
        if (v_ok) {
            const int base = v_mine * BARY + (i2 * NT + j2) * 3;
            gg.w0 = bary_w[base + 0];
            gg.w1 = bary_w[base + 1];
            gg.w2 = bary_w[base + 2];
            gg.i0 = bary_idx[base + 0];
            gg.i1 = bary_idx[base + 1];
            gg.i2 = bary_idx[base + 2];
        } else {
            gg.w0 = gg.w1 = gg.w2 = 0.f;
            gg.i0 = gg.i1 = gg.i2 = 0;
        }
        return gg;
    };

    f16x4 s0v, s1v, s2v;
    auto SIGLOAD = [&](const Gen& gg, int it2, f16x4& o0, f16x4& o1, f16x4& o2) {
        const int itc = (it2 < NCH) ? it2 : (NCH - 1);
        const int icc2 = itc - (itc / 10) * 10;
        const int coff = (icc2 & 1) * 32 + cq * 4;
        o0 = *(const f16x4*)(sig16 + gg.i0 * CIN + coff);
        o1 = *(const f16x4*)(sig16 + gg.i1 * CIN + coff);
        o2 = *(const f16x4*)(sig16 + gg.i2 * CIN + coff);
    };

    // B chunk reg-staging (v7 path, plain layout)
    f16x8 breg0, breg1, breg2, breg3;
    auto BLOADR = [&](int icc2) {
        const _Float16* src = bk + icc2 * 16384 + wn * 2048 + lane * 8;
        breg0 = *(const f16x8*)(src + 0 * 512);
        breg1 = *(const f16x8*)(src + 1 * 512);
        breg2 = *(const f16x8*)(src + 2 * 512);
        breg3 = *(const f16x8*)(src + 3 * 512);
    };
    auto BWRITE = [&](int b) {
        _Float16* dst = &Blds[b][wn * 2048 + lane * 8];
        *(f16x8*)(dst + 0 * 512) = breg0;
        *(f16x8*)(dst + 1 * 512) = breg1;
        *(f16x8*)(dst + 2 * 512) = breg2;
        *(f16x8*)(dst + 3 * 512) = breg3;
    };

    // ---- prologue: chunk 0 into buf0 (A and B); pipeline regs for 1,2 ----
    {
        Gen gz = LOADGEN(0);
        f16x4 t0, t1, t2;
        SIGLOAD(gz, 0, t0, t1, t2);
        f16x4 hv;
        #pragma unroll
        for (int e = 0; e < 4; ++e) {
            float xf = gz.w0 * (float)t0[e] + gz.w1 * (float)t1[e] + gz.w2 * (float)t2[e];
            hv[e] = (_Float16)xf;
        }
        *(f16x4*)&Axs[0][cq >> 1][vt][(cq & 1) * 4] = hv;
    }
    BLOADR(0);
    BWRITE(0);
    Gen gA = LOADGEN(1);            // gen for chunk it+1
    SIGLOAD(gA, 1, s0v, s1v, s2v);  // sig for chunk it+1
    Gen gB = LOADGEN(2);            // gen for chunk it+2
    __syncthreads();

    int ab = 0, cur = 0;
    #pragma unroll 1
    for (int it = 0; it < NCH; ++it) {
        const int j = it / 10;
        const int m = (j + wn) & 7;

        // issue B(it+1) loads first (full MFMA block of flight time)
        const int iccn = (it + 1 < NCH) ? ((it + 1) - ((it + 1) / 10) * 10) : 0;
        if (it + 1 < NCH) BLOADR(iccn);

        // MFMA for chunk it from Axs[ab] / Blds[cur]
        f16x8 afrag[4];
        #pragma unroll
        for (int mf = 0; mf < 4; ++mf)
            afrag[mf] = *(const f16x8*)&Axs[ab][g][mf * 16 + l15][0];

        #pragma unroll
        for (int nf = 0; nf < 4; ++nf) {
            const int col = m * 64 + nf * 16 + l15;
            const f16x8 bfrag = *(const f16x8*)&Blds[cur][col * 32 + g * 8];
            #pragma unroll
            for (int mf = 0; mf < 4; ++mf)
                acc[mf][nf] = __builtin_amdgcn_mfma_f32_16x16x32_f16(
                    afrag[mf], bfrag, acc[mf][nf], 0, 0, 0);
        }

        if (it + 1 < NCH) {
            // A(it+1): x from regs (sig/gen prefetched last chunk) -> other buf
            {
                f16x4 hv;
                #pragma unroll
                for (int e = 0; e < 4; ++e) {
                    float xf = gA.w0 * (float)s0v[e]
                             + gA.w1 * (float)s1v[e]
                             + gA.w2 * (float)s2v[e];
                    hv[e] = (_Float16)xf;
                }
                *(f16x4*)&Axs[ab ^ 1][cq >> 1][vt][(cq & 1) * 4] = hv;
            }
            SIGLOAD(gB, it + 2, s0v, s1v, s2v);   // sig for it+2
            gA = gB;
            gB = LOADGEN(it + 3);                 // gen for it+3
            BWRITE(cur ^ 1);                      // waits vmcnt on breg*
        }

        // ONE barrier per chunk: all LDS writes visible, all reads done
        __syncthreads();
        ab ^= 1; cur ^= 1;
    }

    // ---- epilogue: wave wn owns rotation wn; norms per row ----
    #pragma unroll
    for (int mf = 0; mf < 4; ++mf)
        #pragma unroll
        for (int ri = 0; ri < 4; ++ri) {
            float s = 0.f;
            #pragma unroll
            for (int nf = 0; nf < 4; ++nf) {
                float vv = acc[mf][nf][ri];
                s = fmaf(vv, vv, s);
            }
            #pragma unroll
            for (int off = 1; off < 16; off <<= 1)
                s += __shfl_xor(s, off);
            if (l15 == 0) nrm[mf * 16 + g * 4 + ri][wn] = s;
        }
    __syncthreads();

    if (tid < BM2) {
        const int v = vbase + tid;
        float bn = nrm[tid][0];
        float sec = -1e30f;
        int best = 0;
        #pragma unroll
        for (int k = 1; k < NT; ++k) {
            float nv = nrm[tid][k];
            if (nv > bn)       { sec = bn; bn = nv; best = k; }
            else if (nv > sec) { sec = nv; }
        }
        // gap-err sigma ~3.6e-3 -> ~8 sigma (validated rounds 14-18)
        const bool flag = (bn - sec) <= (3.0e-2f + 4e-4f * bn);
        besti[tid] = flag ? -1 : best;
        if (flag && v < NV) { int p = atomicAdd(wl, 1); wl[1 + p] = v; }
    }
    __syncthreads();

    #pragma unroll
    for (int mf = 0; mf < 4; ++mf)
        #pragma unroll
        for (int ri = 0; ri < 4; ++ri) {
            const int row = mf * 16 + g * 4 + ri;
            const int v   = vbase + row;
            const int bsel = (v < NV) ? besti[row] : -1;
            if (bsel == wn) {
                #pragma unroll
                for (int nf = 0; nf < 4; ++nf) {
                    const int d = nf * 16 + l15;
                    out[v * COUT + d] = fmaxf(acc[mf][nf][ri], 0.0f);
                }
            }
        }
}

// ---------- parallel fp64 refine: one BLOCK (4 waves) per vertex ----------
__global__ __launch_bounds__(256) void geo_refine_f64p(
    const float* __restrict__ signal,
    const float* __restrict__ bary_w,
    const int*   __restrict__ bary_idx,
    const float* __restrict__ kern,
    float*       __restrict__ out,
    const int*   __restrict__ wl,
    int nall)
{
    __shared__ __align__(16) float xs[NR][CIN][NT];
    __shared__ double part[4][NT][COUT];
    __shared__ double convl[NT][COUT];
    __shared__ double nks[NT];
    __shared__ int bestS;

    const int tid  = threadIdx.x;
    const int wave = tid >> 6;
    const int lane = tid & 63;
    const int count = wl ? wl[0] : nall;

    for (int w = blockIdx.x; w < count; w += gridDim.x) {
        const int v = wl ? wl[1 + w] : w;

        for (int ij = wave; ij < NR * NT; ij += 4) {
            const int i = ij >> 3, j = ij & 7;
            const int base = v * BARY + ij * 3;
            const float w0 = bary_w[base], w1 = bary_w[base+1], w2 = bary_w[base+2];
            const int   i0 = bary_idx[base], i1 = bary_idx[base+1], i2 = bary_idx[base+2];
            xs[i][lane][j] = w0 * signal[i0*CIN + lane]
                           + w1 * signal[i1*CIN + lane]
                           + w2 * signal[i2*CIN + lane];
        }
        __syncthreads();

        double acc[NT];
        #pragma unroll
        for (int k = 0; k < NT; ++k) acc[k] = 0.0;

        for (int r = wave * 80; r < wave * 80 + 80; ++r) {
            const int i = r >> 6, c = r & 63;
            const float4 xa = *reinterpret_cast<const float4*>(&xs[i][c][0]);
            const float4 xb = *reinterpret_cast<const float4*>(&xs[i][c][4]);
            const double x8[NT] = {(double)xa.x, (double)xa.y, (double)xa.z, (double)xa.w,
                                   (double)xb.x, (double)xb.y, (double)xb.z, (double)xb.w};
            #pragma unroll
            for (int mm = 0; mm < NT; ++mm) {
                const double kv = (double)kern[((i * NT + mm) * CIN + c) * COUT + lane];
                #pragma unroll
                for (int k = 0; k < NT; ++k)
                    acc[k] = fma(x8[(mm - k + NT) & (NT - 1)], kv, acc[k]);
            }
        }
        #pragma unroll
        for (int k = 0; k < NT; ++k) part[wave][k][lane] = acc[k];
        __syncthreads();

        for (int kd = tid; kd < NT * COUT; kd += 256) {
            const int k = kd >> 6, d = kd & 63;
            convl[k][d] = ((part[0][k][d] + part[1][k][d])
                         + (part[2][k][d] + part[3][k][d]));
        }
        __syncthreads();

        for (int k = wave; k < NT; k += 4) {
            double n = convl[k][lane] * convl[k][lane];
            #pragma unroll
            for (int off = 32; off >= 1; off >>= 1) n += __shfl_xor(n, off);
            if (lane == 0) nks[k] = n;
        }
        __syncthreads();

        if (tid == 0) {
            int best = 0; double bn = nks[0];
            #pragma unroll
            for (int k = 1; k < NT; ++k)
                if (nks[k] > bn) { bn = nks[k]; best = k; }
            bestS = best;
        }
        __syncthreads();

        if (tid < COUT) out[v * COUT + tid] = fmaxf((float)convl[bestS][tid], 0.0f);
        __syncthreads();
    }
}

extern "C" void kernel_launch(void* const* d_in, const int* in_sizes, int n_in,
                              void* d_out, int out_size, void* d_ws, size_t ws_size,
                              hipStream_t stream) {
    const float* signal   = (const float*)d_in[0];
    const float* bary_w   = (const float*)d_in[1];
    const int*   bary_idx = (const int*)d_in[2];
    const float* kern     = (const float*)d_in[3];
    float* out = (float*)d_out;

    if (ws_size >= (size_t)WS_NEED8) {
        int* wl = (int*)d_ws;
        _Float16* bk    = (_Float16*)((char*)d_ws + WL_BYTES);
        _Float16* sig16 = (_Float16*)((char*)d_ws + WL_BYTES + 2u * BK_ELEMS);
        hipMemsetAsync(wl, 0, sizeof(int), stream);
        build_bk7<<<dim3(BK_ELEMS / 256), dim3(256), 0, stream>>>(kern, bk);
        build_sig16<<<dim3(NV * CIN / 256), dim3(256), 0, stream>>>(signal, sig16);
        geo_mfma15<<<dim3(NBLK2), dim3(512), 0, stream>>>(
            bary_w, bary_idx, sig16, bk, out, wl);
        geo_refine_f64p<<<dim3(1024), dim3(256), 0, stream>>>(
            signal, bary_w, bary_idx, kern, out, wl, 0);
    } else {
        geo_refine_f64p<<<dim3(1024), dim3(256), 0, stream>>>(
            signal, bary_w, bary_idx, kern, out, nullptr, NV);
    }
}

// Round 20
// 376.469 us; speedup vs baseline: 1.3826x; 1.3826x over previous
//
#include <hip/hip_runtime.h>

#define NV   50000
#define NR   5
#define NT   8
#define CIN  64
#define COUT 64
#define BARY (NR*NT*3)      // 120
#define BK_ELEMS (NR*CIN*NT*COUT)   // 163840 fp16 (320 KB) — L2-resident
#define BM2  64
#define NBLK2 ((NV + BM2 - 1) / BM2)   // 782
#define NCH7 80             // chunks: (j 0..7) x (icc 0..9), K=32 each

#define WL_BYTES 262144
#define SIG16_BYTES (NV*CIN*2)                            // 6.4 MB
#define WS_NEED7 (WL_BYTES + 2u*BK_ELEMS + SIG16_BYTES)   // ~7.0 MB

typedef _Float16 f16x8 __attribute__((ext_vector_type(8)));
typedef _Float16 f16x4 __attribute__((ext_vector_type(4)));
typedef float    f32x4 __attribute__((ext_vector_type(4)));

// ---------- K0a: kernel -> fp16 ws, chunked [icc][col=m*64+d][ck] ----------
__global__ __launch_bounds__(256) void build_bk7(
    const float* __restrict__ kern, _Float16* __restrict__ bk)
{
    int e   = blockIdx.x * 256 + threadIdx.x;   // icc*16384 + col*32 + ck
    int ck  = e & 31;
    int col = (e >> 5) & 511;
    int icc = e >> 14;
    int i   = icc >> 1;
    int c   = (icc & 1) * 32 + ck;
    int m   = col >> 6;
    int d   = col & 63;
    bk[e] = (_Float16)kern[((i * NT + m) * CIN + c) * COUT + d];
}

// ---------- K0b: signal -> fp16 ----------
__global__ __launch_bounds__(256) void build_sig16(
    const float* __restrict__ signal, _Float16* __restrict__ sig16)
{
    int e = blockIdx.x * 256 + threadIdx.x;
    sig16[e] = (_Float16)signal[e];
}

// ---------- main: v7 BYTE-EXACT (round-11, 323us, no-spill) ----------
__global__ __launch_bounds__(512, 4) void geo_mfma7(
    const float* __restrict__ bary_w,
    const int*   __restrict__ bary_idx,
    const _Float16* __restrict__ sig16,
    const _Float16* __restrict__ bk,
    float* __restrict__ out,
    int*   __restrict__ wl)
{
    __shared__ __align__(16) _Float16 Blds[2][16384];   // 2 x 32 KB
    __shared__ __align__(16) _Float16 Axs[4][BM2][8];   // 4 KB (K=32, single-buf)
    __shared__ float nrm[BM2][NT];                      // 2 KB
    __shared__ int   besti[BM2];

    const int tid  = threadIdx.x;
    const int lane = tid & 63;
    const int wn   = tid >> 6;         // wave wn owns rotation k=wn
    const int g    = lane >> 4;
    const int l15  = lane & 15;
    const int vbase = blockIdx.x * BM2;

    // A-staging mapping: thread -> (vertex vt, ck-quad cq); 4 channels each
    const int vt = tid >> 3;
    const int cq = tid & 7;
    const int v_mine = vbase + vt;
    const bool v_ok = (v_mine < NV);

    f32x4 acc[4][4];
    {
        f32x4 z = {0.f, 0.f, 0.f, 0.f};
        #pragma unroll
        for (int mf = 0; mf < 4; ++mf)
            #pragma unroll
            for (int nf = 0; nf < 4; ++nf) acc[mf][nf] = z;
    }

    struct Gen { float w0, w1, w2; int i0, i1, i2; };
    auto LOADGEN = [&](int it2) -> Gen {
        Gen gg;
        const int itc = (it2 < NCH7) ? it2 : (NCH7 - 1);
        const int j2   = itc / 10;
        const int icc2 = itc - j2 * 10;
        const int i2   = icc2 >> 1;
        if (v_ok) {
            const int base = v_mine * BARY + (i2 * NT + j2) * 3;
            gg.w0 = bary_w[base + 0];
            gg.w1 = bary_w[base + 1];
            gg.w2 = bary_w[base + 2];
            gg.i0 = bary_idx[base + 0];
            gg.i1 = bary_idx[base + 1];
            gg.i2 = bary_idx[base + 2];
        } else {
            gg.w0 = gg.w1 = gg.w2 = 0.f;
            gg.i0 = gg.i1 = gg.i2 = 0;
        }
        return gg;
    };

    // sig slice for chunk: 4 ch at c = (icc&1)*32 + cq*4
    f16x4 sA0, sA1, sA2, sB0, sB1, sB2;
    auto SIGLOAD = [&](const Gen& gg, int it2, f16x4& o0, f16x4& o1, f16x4& o2) {
        const int itc = (it2 < NCH7) ? it2 : (NCH7 - 1);
        const int icc2 = itc - (itc / 10) * 10;
        const int coff = (icc2 & 1) * 32 + cq * 4;
        o0 = *(const f16x4*)(sig16 + gg.i0 * CIN + coff);
        o1 = *(const f16x4*)(sig16 + gg.i1 * CIN + coff);
        o2 = *(const f16x4*)(sig16 + gg.i2 * CIN + coff);
    };

    // B chunk reg-staging: wave w covers elems w*2048 + r*512 + lane*8, r=0..3
    f16x8 breg0, breg1, breg2, breg3;
    auto BLOADR = [&](int icc2) {
        const _Float16* src = bk + icc2 * 16384 + wn * 2048 + lane * 8;
        breg0 = *(const f16x8*)(src + 0 * 512);
        breg1 = *(const f16x8*)(src + 1 * 512);
        breg2 = *(const f16x8*)(src + 2 * 512);
        breg3 = *(const f16x8*)(src + 3 * 512);
    };
    auto BWRITE = [&](int b) {
        _Float16* dst = &Blds[b][wn * 2048 + lane * 8];
        *(f16x8*)(dst + 0 * 512) = breg0;
        *(f16x8*)(dst + 1 * 512) = breg1;
        *(f16x8*)(dst + 2 * 512) = breg2;
        *(f16x8*)(dst + 3 * 512) = breg3;
    };

    // ---- prologue ----
    Gen g0 = LOADGEN(0);
    Gen g1 = LOADGEN(1);
    SIGLOAD(g0, 0, sA0, sA1, sA2);
    BLOADR(0);
    BWRITE(0);
    __syncthreads();

    int cur = 0;
    for (int it = 0; it < NCH7; ++it) {
        const int j   = it / 10;
        const int icc = it - j * 10;
        const int m   = (j + wn) & 7;
        (void)icc;

        // ---- phase1: x(it) from regs -> Axs; issue next sig/bary ----
        {
            f16x4 hv;
            #pragma unroll
            for (int e = 0; e < 4; ++e) {
                float xf = g0.w0 * (float)sA0[e]
                         + g0.w1 * (float)sA1[e]
                         + g0.w2 * (float)sA2[e];
                hv[e] = (_Float16)xf;
            }
            *(f16x4*)&Axs[cq >> 1][vt][(cq & 1) * 4] = hv;
        }
        SIGLOAD(g1, it + 1, sB0, sB1, sB2);
        Gen g2 = LOADGEN(it + 2);
        __syncthreads();   // bar1: Axs ready (drains stage loads too)

        // ---- phase2: issue B(it+1) loads early; MFMA from LDS; write B ----
        const int iccn = (it + 1 < NCH7) ? ((it + 1) - ((it + 1) / 10) * 10) : 0;
        if (it + 1 < NCH7) BLOADR(iccn);

        f16x8 afrag[4];
        #pragma unroll
        for (int mf = 0; mf < 4; ++mf)
            afrag[mf] = *(const f16x8*)&Axs[g][mf * 16 + l15][0];

        #pragma unroll
        for (int nf = 0; nf < 4; ++nf) {
            const int col = m * 64 + nf * 16 + l15;
            const f16x8 bfrag = *(const f16x8*)&Blds[cur][col * 32 + g * 8];
            #pragma unroll
            for (int mf = 0; mf < 4; ++mf)
                acc[mf][nf] = __builtin_amdgcn_mfma_f32_16x16x32_f16(
                    afrag[mf], bfrag, acc[mf][nf], 0, 0, 0);
        }

        if (it + 1 < NCH7) BWRITE(cur ^ 1);   // waits vmcnt on breg*
        __syncthreads();   // bar2: B(it+1) visible; Axs free

        // rotate pipeline
        g0 = g1; g1 = g2;
        sA0 = sB0; sA1 = sB1; sA2 = sB2;
        cur ^= 1;
    }

    // ---- epilogue: wave wn owns rotation wn; norms per row ----
    #pragma unroll
    for (int mf = 0; mf < 4; ++mf)
        #pragma unroll
        for (int ri = 0; ri < 4; ++ri) {
            float s = 0.f;
            #pragma unroll
            for (int nf = 0; nf < 4; ++nf) {
                float vv = acc[mf][nf][ri];
                s = fmaf(vv, vv, s);
            }
            #pragma unroll
            for (int off = 1; off < 16; off <<= 1)
                s += __shfl_xor(s, off);
            if (l15 == 0) nrm[mf * 16 + g * 4 + ri][wn] = s;
        }
    __syncthreads();

    if (tid < BM2) {
        const int v = vbase + tid;
        float bn = nrm[tid][0];
        float sec = -1e30f;
        int best = 0;
        #pragma unroll
        for (int k = 1; k < NT; ++k) {
            float nv = nrm[tid][k];
            if (nv > bn)       { sec = bn; bn = nv; best = k; }
            else if (nv > sec) { sec = nv; }
        }
        // gap-err sigma ~3.6e-3 -> ~8 sigma (validated rounds 14-18, absmax 0.0156)
        const bool flag = (bn - sec) <= (3.0e-2f + 4e-4f * bn);
        besti[tid] = flag ? -1 : best;
        if (flag && v < NV) { int p = atomicAdd(wl, 1); wl[1 + p] = v; }
    }
    __syncthreads();

    #pragma unroll
    for (int mf = 0; mf < 4; ++mf)
        #pragma unroll
        for (int ri = 0; ri < 4; ++ri) {
            const int row = mf * 16 + g * 4 + ri;
            const int v   = vbase + row;
            const int bsel = (v < NV) ? besti[row] : -1;
            if (bsel == wn) {
                #pragma unroll
                for (int nf = 0; nf < 4; ++nf) {
                    const int d = nf * 16 + l15;
                    out[v * COUT + d] = fmaxf(acc[mf][nf][ri], 0.0f);
                }
            }
        }
}

// ---------- parallel fp64 refine: one BLOCK (4 waves) per vertex ----------
__global__ __launch_bounds__(256) void geo_refine_f64p(
    const float* __restrict__ signal,
    const float* __restrict__ bary_w,
    const int*   __restrict__ bary_idx,
    const float* __restrict__ kern,
    float*       __restrict__ out,
    const int*   __restrict__ wl,
    int nall)
{
    __shared__ __align__(16) float xs[NR][CIN][NT];
    __shared__ double part[4][NT][COUT];
    __shared__ double convl[NT][COUT];
    __shared__ double nks[NT];
    __shared__ int bestS;

    const int tid  = threadIdx.x;
    const int wave = tid >> 6;
    const int lane = tid & 63;
    const int count = wl ? wl[0] : nall;

    for (int w = blockIdx.x; w < count; w += gridDim.x) {
        const int v = wl ? wl[1 + w] : w;

        for (int ij = wave; ij < NR * NT; ij += 4) {
            const int i = ij >> 3, j = ij & 7;
            const int base = v * BARY + ij * 3;
            const float w0 = bary_w[base], w1 = bary_w[base+1], w2 = bary_w[base+2];
            const int   i0 = bary_idx[base], i1 = bary_idx[base+1], i2 = bary_idx[base+2];
            xs[i][lane][j] = w0 * signal[i0*CIN + lane]
                           + w1 * signal[i1*CIN + lane]
                           + w2 * signal[i2*CIN + lane];
        }
        __syncthreads();

        double acc[NT];
        #pragma unroll
        for (int k = 0; k < NT; ++k) acc[k] = 0.0;

        for (int r = wave * 80; r < wave * 80 + 80; ++r) {
            const int i = r >> 6, c = r & 63;
            const float4 xa = *reinterpret_cast<const float4*>(&xs[i][c][0]);
            const float4 xb = *reinterpret_cast<const float4*>(&xs[i][c][4]);
            const double x8[NT] = {(double)xa.x, (double)xa.y, (double)xa.z, (double)xa.w,
                                   (double)xb.x, (double)xb.y, (double)xb.z, (double)xb.w};
            #pragma unroll
            for (int mm = 0; mm < NT; ++mm) {
                const double kv = (double)kern[((i * NT + mm) * CIN + c) * COUT + lane];
                #pragma unroll
                for (int k = 0; k < NT; ++k)
                    acc[k] = fma(x8[(mm - k + NT) & (NT - 1)], kv, acc[k]);
            }
        }
        #pragma unroll
        for (int k = 0; k < NT; ++k) part[wave][k][lane] = acc[k];
        __syncthreads();

        for (int kd = tid; kd < NT * COUT; kd += 256) {
            const int k = kd >> 6, d = kd & 63;
            convl[k][d] = ((part[0][k][d] + part[1][k][d])
                         + (part[2][k][d] + part[3][k][d]));
        }
        __syncthreads();

        for (int k = wave; k < NT; k += 4) {
            double n = convl[k][lane] * convl[k][lane];
            #pragma unroll
            for (int off = 32; off >= 1; off >>= 1) n += __shfl_xor(n, off);
            if (lane == 0) nks[k] = n;
        }
        __syncthreads();

        if (tid == 0) {
            int best = 0; double bn = nks[0];
            #pragma unroll
            for (int k = 1; k < NT; ++k)
                if (nks[k] > bn) { bn = nks[k]; best = k; }
            bestS = best;
        }
        __syncthreads();

        if (tid < COUT) out[v * COUT + tid] = fmaxf((float)convl[bestS][tid], 0.0f);
        __syncthreads();
    }
}

extern "C" void kernel_launch(void* const* d_in, const int* in_sizes, int n_in,
                              void* d_out, int out_size, void* d_ws, size_t ws_size,
                              hipStream_t stream) {
    const float* signal   = (const float*)d_in[0];
    const float* bary_w   = (const float*)d_in[1];
    const int*   bary_idx = (const int*)d_in[2];
    const float* kern     = (const float*)d_in[3];
    float* out = (float*)d_out;

    if (ws_size >= (size_t)WS_NEED7) {
        int* wl = (int*)d_ws;
        _Float16* bk    = (_Float16*)((char*)d_ws + WL_BYTES);
        _Float16* sig16 = (_Float16*)((char*)d_ws + WL_BYTES + 2u * BK_ELEMS);
        hipMemsetAsync(wl, 0, sizeof(int), stream);
        build_bk7<<<dim3(BK_ELEMS / 256), dim3(256), 0, stream>>>(kern, bk);
        build_sig16<<<dim3(NV * CIN / 256), dim3(256), 0, stream>>>(signal, sig16);
        geo_mfma7<<<dim3(NBLK2), dim3(512), 0, stream>>>(
            bary_w, bary_idx, sig16, bk, out, wl);
        geo_refine_f64p<<<dim3(1024), dim3(256), 0, stream>>>(
            signal, bary_w, bary_idx, kern, out, wl, 0);
    } else {
        geo_refine_f64p<<<dim3(1024), dim3(256), 0, stream>>>(
            signal, bary_w, bary_idx, kern, out, nullptr, NV);
    }
}

// Round 21
// 327.897 us; speedup vs baseline: 1.5874x; 1.1481x over previous
//
#include <hip/hip_runtime.h>

#define NV   50000
#define NR   5
#define NT   8
#define CIN  64
#define COUT 64
#define BARY (NR*NT*3)      // 120
#define BK_ELEMS (NR*CIN*NT*COUT)   // 163840 fp16 (320 KB) — L2-resident
#define BM2  64
#define NBLK2 ((NV + BM2 - 1) / BM2)   // 782
#define NICC 10             // K-chunks (icc), 32 K-elems each
#define NCH  80             // iterations: icc-OUTER x j-INNER (B reused across j!)

#define WL_BYTES 262144
#define SIG16_BYTES (NV*CIN*2)                            // 6.4 MB
#define WS_NEED7 (WL_BYTES + 2u*BK_ELEMS + SIG16_BYTES)   // ~7.0 MB

typedef _Float16 f16x8 __attribute__((ext_vector_type(8)));
typedef _Float16 f16x4 __attribute__((ext_vector_type(4)));
typedef float    f32x4 __attribute__((ext_vector_type(4)));

// ---------- K0a: kernel -> fp16 ws, chunked [icc][col=m*64+d][ck] (v7 layout) ----------
__global__ __launch_bounds__(256) void build_bk7(
    const float* __restrict__ kern, _Float16* __restrict__ bk)
{
    int e   = blockIdx.x * 256 + threadIdx.x;   // icc*16384 + col*32 + ck
    int ck  = e & 31;
    int col = (e >> 5) & 511;
    int icc = e >> 14;
    int i   = icc >> 1;
    int c   = (icc & 1) * 32 + ck;
    int m   = col >> 6;
    int d   = col & 63;
    bk[e] = (_Float16)kern[((i * NT + m) * CIN + c) * COUT + d];
}

// ---------- K0b: signal -> fp16 ----------
__global__ __launch_bounds__(256) void build_sig16(
    const float* __restrict__ signal, _Float16* __restrict__ sig16)
{
    int e = blockIdx.x * 256 + threadIdx.x;
    sig16[e] = (_Float16)signal[e];
}

// ---------- main v16 = v7 with icc-OUTER / j-INNER: B staged 10x not 80x ----------
// Key fact: Blds[icc] holds ALL rotations' columns; j only selects which
// col-block each wave reads (m=(j+wn)&7). So B staging is hoisted out of
// the j loop: 7 of 8 iterations have NO B traffic/vmcnt stall. A path,
// barriers, and register inventory byte-identical to v7 (proven no-spill).
__global__ __launch_bounds__(512, 4) void geo_mfma16(
    const float* __restrict__ bary_w,
    const int*   __restrict__ bary_idx,
    const _Float16* __restrict__ sig16,
    const _Float16* __restrict__ bk,
    float* __restrict__ out,
    int*   __restrict__ wl)
{
    __shared__ __align__(16) _Float16 Blds[2][16384];   // 2 x 32 KB
    __shared__ __align__(16) _Float16 Axs[4][BM2][8];   // 4 KB (single-buf)
    __shared__ float nrm[BM2][NT];                      // 2 KB
    __shared__ int   besti[BM2];

    const int tid  = threadIdx.x;
    const int lane = tid & 63;
    const int wn   = tid >> 6;         // wave wn owns rotation k=wn
    const int g    = lane >> 4;
    const int l15  = lane & 15;
    const int vbase = blockIdx.x * BM2;

    // A-staging mapping: thread -> (vertex vt, ck-quad cq); 4 channels each
    const int vt = tid >> 3;
    const int cq = tid & 7;
    const int v_mine = vbase + vt;
    const bool v_ok = (v_mine < NV);

    f32x4 acc[4][4];
    {
        f32x4 z = {0.f, 0.f, 0.f, 0.f};
        #pragma unroll
        for (int mf = 0; mf < 4; ++mf)
            #pragma unroll
            for (int nf = 0; nf < 4; ++nf) acc[mf][nf] = z;
    }

    // iteration order: it = icc*8 + j  (icc outer, j inner)
    struct Gen { float w0, w1, w2; int i0, i1, i2; };
    auto LOADGEN = [&](int it2) -> Gen {
        Gen gg;
        const int itc = (it2 < NCH) ? it2 : (NCH - 1);
        const int icc2 = itc >> 3;
        const int j2   = itc & 7;
        const int i2   = icc2 >> 1;
        if (v_ok) {
            const int base = v_mine * BARY + (i2 * NT + j2) * 3;
            gg.w0 = bary_w[base + 0];
            gg.w1 = bary_w[base + 1];
            gg.w2 = bary_w[base + 2];
            gg.i0 = bary_idx[base + 0];
            gg.i1 = bary_idx[base + 1];
            gg.i2 = bary_idx[base + 2];
        } else {
            gg.w0 = gg.w1 = gg.w2 = 0.f;
            gg.i0 = gg.i1 = gg.i2 = 0;
        }
        return gg;
    };

    // sig slice: 4 ch at c = (icc&1)*32 + cq*4
    f16x4 sA0, sA1, sA2, sB0, sB1, sB2;
    auto SIGLOAD = [&](const Gen& gg, int it2, f16x4& o0, f16x4& o1, f16x4& o2) {
        const int itc = (it2 < NCH) ? it2 : (NCH - 1);
        const int icc2 = itc >> 3;
        const int coff = (icc2 & 1) * 32 + cq * 4;
        o0 = *(const f16x4*)(sig16 + gg.i0 * CIN + coff);
        o1 = *(const f16x4*)(sig16 + gg.i1 * CIN + coff);
        o2 = *(const f16x4*)(sig16 + gg.i2 * CIN + coff);
    };

    // B chunk reg-staging (v7 pattern, now invoked once per icc)
    f16x8 breg0, breg1, breg2, breg3;
    auto BLOADR = [&](int icc2) {
        const _Float16* src = bk + icc2 * 16384 + wn * 2048 + lane * 8;
        breg0 = *(const f16x8*)(src + 0 * 512);
        breg1 = *(const f16x8*)(src + 1 * 512);
        breg2 = *(const f16x8*)(src + 2 * 512);
        breg3 = *(const f16x8*)(src + 3 * 512);
    };
    auto BWRITE = [&](int b) {
        _Float16* dst = &Blds[b][wn * 2048 + lane * 8];
        *(f16x8*)(dst + 0 * 512) = breg0;
        *(f16x8*)(dst + 1 * 512) = breg1;
        *(f16x8*)(dst + 2 * 512) = breg2;
        *(f16x8*)(dst + 3 * 512) = breg3;
    };

    // ---- prologue ----
    Gen g0 = LOADGEN(0);
    Gen g1 = LOADGEN(1);
    SIGLOAD(g0, 0, sA0, sA1, sA2);
    BLOADR(0);
    BWRITE(0);
    __syncthreads();

    int cur = 0;
    #pragma unroll 1
    for (int it = 0; it < NCH; ++it) {
        const int icc = it >> 3;
        const int j   = it & 7;
        const int m   = (j + wn) & 7;
        const bool stageB = (j == 7) && (icc + 1 < NICC);

        // ---- phase1: x(it) from regs -> Axs; issue next sig/bary ----
        {
            f16x4 hv;
            #pragma unroll
            for (int e = 0; e < 4; ++e) {
                float xf = g0.w0 * (float)sA0[e]
                         + g0.w1 * (float)sA1[e]
                         + g0.w2 * (float)sA2[e];
                hv[e] = (_Float16)xf;
            }
            *(f16x4*)&Axs[cq >> 1][vt][(cq & 1) * 4] = hv;
        }
        SIGLOAD(g1, it + 1, sB0, sB1, sB2);
        Gen g2 = LOADGEN(it + 2);
        __syncthreads();   // bar1: Axs ready

        // ---- phase2: (every 8th iter) issue B(icc+1); MFMA from LDS ----
        if (stageB) BLOADR(icc + 1);

        f16x8 afrag[4];
        #pragma unroll
        for (int mf = 0; mf < 4; ++mf)
            afrag[mf] = *(const f16x8*)&Axs[g][mf * 16 + l15][0];

        #pragma unroll
        for (int nf = 0; nf < 4; ++nf) {
            const int col = m * 64 + nf * 16 + l15;
            const f16x8 bfrag = *(const f16x8*)&Blds[cur][col * 32 + g * 8];
            #pragma unroll
            for (int mf = 0; mf < 4; ++mf)
                acc[mf][nf] = __builtin_amdgcn_mfma_f32_16x16x32_f16(
                    afrag[mf], bfrag, acc[mf][nf], 0, 0, 0);
        }

        if (stageB) BWRITE(cur ^ 1);   // waits vmcnt on breg* (1 in 8 iters)
        __syncthreads();   // bar2: B(icc+1) visible (when staged); Axs free

        // rotate pipeline
        g0 = g1; g1 = g2;
        sA0 = sB0; sA1 = sB1; sA2 = sB2;
        if (j == 7) cur ^= 1;
    }

    // ---- epilogue: wave wn owns rotation wn; norms per row ----
    #pragma unroll
    for (int mf = 0; mf < 4; ++mf)
        #pragma unroll
        for (int ri = 0; ri < 4; ++ri) {
            float s = 0.f;
            #pragma unroll
            for (int nf = 0; nf < 4; ++nf) {
                float vv = acc[mf][nf][ri];
                s = fmaf(vv, vv, s);
            }
            #pragma unroll
            for (int off = 1; off < 16; off <<= 1)
                s += __shfl_xor(s, off);
            if (l15 == 0) nrm[mf * 16 + g * 4 + ri][wn] = s;
        }
    __syncthreads();

    if (tid < BM2) {
        const int v = vbase + tid;
        float bn = nrm[tid][0];
        float sec = -1e30f;
        int best = 0;
        #pragma unroll
        for (int k = 1; k < NT; ++k) {
            float nv = nrm[tid][k];
            if (nv > bn)       { sec = bn; bn = nv; best = k; }
            else if (nv > sec) { sec = nv; }
        }
        // gap-err sigma ~3.6e-3 -> ~8 sigma (validated rounds 14-20, absmax 0.0156)
        const bool flag = (bn - sec) <= (3.0e-2f + 4e-4f * bn);
        besti[tid] = flag ? -1 : best;
        if (flag && v < NV) { int p = atomicAdd(wl, 1); wl[1 + p] = v; }
    }
    __syncthreads();

    #pragma unroll
    for (int mf = 0; mf < 4; ++mf)
        #pragma unroll
        for (int ri = 0; ri < 4; ++ri) {
            const int row = mf * 16 + g * 4 + ri;
            const int v   = vbase + row;
            const int bsel = (v < NV) ? besti[row] : -1;
            if (bsel == wn) {
                #pragma unroll
                for (int nf = 0; nf < 4; ++nf) {
                    const int d = nf * 16 + l15;
                    out[v * COUT + d] = fmaxf(acc[mf][nf][ri], 0.0f);
                }
            }
        }
}

// ---------- parallel fp64 refine: one BLOCK (4 waves) per vertex ----------
__global__ __launch_bounds__(256) void geo_refine_f64p(
    const float* __restrict__ signal,
    const float* __restrict__ bary_w,
    const int*   __restrict__ bary_idx,
    const float* __restrict__ kern,
    float*       __restrict__ out,
    const int*   __restrict__ wl,
    int nall)
{
    __shared__ __align__(16) float xs[NR][CIN][NT];
    __shared__ double part[4][NT][COUT];
    __shared__ double convl[NT][COUT];
    __shared__ double nks[NT];
    __shared__ int bestS;

    const int tid  = threadIdx.x;
    const int wave = tid >> 6;
    const int lane = tid & 63;
    const int count = wl ? wl[0] : nall;

    for (int w = blockIdx.x; w < count; w += gridDim.x) {
        const int v = wl ? wl[1 + w] : w;

        for (int ij = wave; ij < NR * NT; ij += 4) {
            const int i = ij >> 3, j = ij & 7;
            const int base = v * BARY + ij * 3;
            const float w0 = bary_w[base], w1 = bary_w[base+1], w2 = bary_w[base+2];
            const int   i0 = bary_idx[base], i1 = bary_idx[base+1], i2 = bary_idx[base+2];
            xs[i][lane][j] = w0 * signal[i0*CIN + lane]
                           + w1 * signal[i1*CIN + lane]
                           + w2 * signal[i2*CIN + lane];
        }
        __syncthreads();

        double acc[NT];
        #pragma unroll
        for (int k = 0; k < NT; ++k) acc[k] = 0.0;

        for (int r = wave * 80; r < wave * 80 + 80; ++r) {
            const int i = r >> 6, c = r & 63;
            const float4 xa = *reinterpret_cast<const float4*>(&xs[i][c][0]);
            const float4 xb = *reinterpret_cast<const float4*>(&xs[i][c][4]);
            const double x8[NT] = {(double)xa.x, (double)xa.y, (double)xa.z, (double)xa.w,
                                   (double)xb.x, (double)xb.y, (double)xb.z, (double)xb.w};
            #pragma unroll
            for (int mm = 0; mm < NT; ++mm) {
                const double kv = (double)kern[((i * NT + mm) * CIN + c) * COUT + lane];
                #pragma unroll
                for (int k = 0; k < NT; ++k)
                    acc[k] = fma(x8[(mm - k + NT) & (NT - 1)], kv, acc[k]);
            }
        }
        #pragma unroll
        for (int k = 0; k < NT; ++k) part[wave][k][lane] = acc[k];
        __syncthreads();

        for (int kd = tid; kd < NT * COUT; kd += 256) {
            const int k = kd >> 6, d = kd & 63;
            convl[k][d] = ((part[0][k][d] + part[1][k][d])
                         + (part[2][k][d] + part[3][k][d]));
        }
        __syncthreads();

        for (int k = wave; k < NT; k += 4) {
            double n = convl[k][lane] * convl[k][lane];
            #pragma unroll
            for (int off = 32; off >= 1; off >>= 1) n += __shfl_xor(n, off);
            if (lane == 0) nks[k] = n;
        }
        __syncthreads();

        if (tid == 0) {
            int best = 0; double bn = nks[0];
            #pragma unroll
            for (int k = 1; k < NT; ++k)
                if (nks[k] > bn) { bn = nks[k]; best = k; }
            bestS = best;
        }
        __syncthreads();

        if (tid < COUT) out[v * COUT + tid] = fmaxf((float)convl[bestS][tid], 0.0f);
        __syncthreads();
    }
}

extern "C" void kernel_launch(void* const* d_in, const int* in_sizes, int n_in,
                              void* d_out, int out_size, void* d_ws, size_t ws_size,
                              hipStream_t stream) {
    const float* signal   = (const float*)d_in[0];
    const float* bary_w   = (const float*)d_in[1];
    const int*   bary_idx = (const int*)d_in[2];
    const float* kern     = (const float*)d_in[3];
    float* out = (float*)d_out;

    if (ws_size >= (size_t)WS_NEED7) {
        int* wl = (int*)d_ws;
        _Float16* bk    = (_Float16*)((char*)d_ws + WL_BYTES);
        _Float16* sig16 = (_Float16*)((char*)d_ws + WL_BYTES + 2u * BK_ELEMS);
        hipMemsetAsync(wl, 0, sizeof(int), stream);
        build_bk7<<<dim3(BK_ELEMS / 256), dim3(256), 0, stream>>>(kern, bk);
        build_sig16<<<dim3(NV * CIN / 256), dim3(256), 0, stream>>>(signal, sig16);
        geo_mfma16<<<dim3(NBLK2), dim3(512), 0, stream>>>(
            bary_w, bary_idx, sig16, bk, out, wl);
        geo_refine_f64p<<<dim3(1024), dim3(256), 0, stream>>>(
            signal, bary_w, bary_idx, kern, out, wl, 0);
    } else {
        geo_refine_f64p<<<dim3(1024), dim3(256), 0, stream>>>(
            signal, bary_w, bary_idx, kern, out, nullptr, NV);
    }
}